// Round 10
// baseline (203.290 us; speedup 1.0000x reference)
//
#include <hip/hip_runtime.h>

// PartialGConv: partial temporal conv (TK=9, pad 4) + mask-ratio + graph einsum.
// FUSED kernel: bf16 implicit-GEMM (MFMA 16x16x32, BM=192 x BN=208(8t) x K=576)
// + MFMA (k,v)-contraction epilogue. r10: BARRIER-FREE K-loop — A fragments are
// read per-step straight from L2-hot wb into registers (1-step reg prefetch);
// B lives in the once-staged xwin. No in-loop barriers or vmcnt drains.
//
// ws layout (bytes):
//   xmr  u16[32][6656][64]  @0          x*mask bf16 row-major, padded rows
//   wb   u16[192][576]      @27,262,976 weights bf16, k=dt*64+cin (PLAIN layout)
//   msum f32[32][6400]      @27,484,160 sum_cin mask
//   s    f32[32][6400]      @28,303,360 576/(upd+eps)*uc^2
//   mr   f32[32][6400]      @29,122,560 mask_ratio
//   mb   f32[32][6400]      @29,941,760 m_bool
//   Bc   f32[32][3][256][25]@30,760,960 sum_v uc*A[k,v,w]

typedef unsigned short u16;
typedef unsigned int u32;
typedef short short8 __attribute__((ext_vector_type(8)));
typedef float f32x4 __attribute__((ext_vector_type(4)));

#define TV 6400
#define KC 192
#define KDIM 576
#define NPADT 6656          // 100 front pad + 6400 + 156 back pad
#define Y_SIZE 13107200
#define MB_OFF 13109075     // Y_SIZE + 1875

#define OFF_WB   27262976
#define OFF_MSUM 27484160
#define OFF_S    28303360
#define OFF_MR   29122560
#define OFF_MB   29941760
#define OFF_BC   30760960

// LDS map (63,136 B total).  K-loop: xwin [0,52224).
// Epilogue aliases: Pl u16[64][336] @0 (43,008 B); Ys f32[32][201] @0;
// misc @52224: Ab 6144 | Bcs 2400 | mrs 800 | bias 768 | ss 800.
#define L_AB    52224
#define L_BCS   58368
#define L_MRS   60768
#define L_BIAS  61568
#define L_SS    62336

#define VMCNT(N) asm volatile("s_waitcnt vmcnt(" #N ")" ::: "memory")

__device__ __forceinline__ u16 f2bf(float f) {
  u32 u = __builtin_bit_cast(u32, f);
  u = (u + 0x7FFFu + ((u >> 16) & 1u)) >> 16;   // RTNE
  return (u16)u;
}
__device__ __forceinline__ float bf2f(u16 h) {
  return __builtin_bit_cast(float, (u32)h << 16);
}
__device__ __forceinline__ void gload_lds16(const u16* g, u16* l) {
  __builtin_amdgcn_global_load_lds(
      (const __attribute__((address_space(1))) u32*)(const void*)g,
      (__attribute__((address_space(3))) u32*)(void*)l, 16, 0, 0);
}

// ---- zero the temporal pad rows of xmr --------------------------------------
__global__ void k_pad(u16* __restrict__ xmr) {
  int i = blockIdx.x * 256 + threadIdx.x;       // 65536 uint4
  if (i >= 65536) return;
  int n = i >> 11, r = i & 2047;                // 256 pad rows x 8 uint4
  int row = r >> 3, c = r & 7;
  int tvrow = (row < 100) ? row : (6400 + row); // front 0..99 / back 6500..6655
  uint4 z; z.x = z.y = z.z = z.w = 0u;
  *(uint4*)(xmr + ((size_t)n * NPADT + tvrow) * 64 + c * 8) = z;
}

// ---- xmr = bf16(x*mask) row-major [tvp][64] + msum = sum_cin mask ------------
__global__ void k_xmT(const float* __restrict__ x, const float* __restrict__ mask,
                      u16* __restrict__ xmr, float* __restrict__ msum) {
  const int tvb = blockIdx.x, n = blockIdx.y;   // grid (100, 32), block 256
  const int tvl = threadIdx.x & 63, q = threadIdx.x >> 6;  // 4 quads of 16 cin
  const int tv = tvb * 64 + tvl;
  const float* xp = x + ((size_t)n * 64 + q * 16) * TV + tv;
  const float* mp = mask + ((size_t)n * 64 + q * 16) * TV + tv;
  u16 vals[16];
  float msacc = 0.f;
#pragma unroll
  for (int j = 0; j < 16; ++j) {                // coalesced: lanes = consecutive tv
    float xv = xp[(size_t)j * TV];
    float mv = mp[(size_t)j * TV];
    msacc += mv;
    vals[j] = f2bf(xv * mv);
  }
  uint4 lo, hi;
  lo.x = vals[0] | ((u32)vals[1] << 16);  lo.y = vals[2] | ((u32)vals[3] << 16);
  lo.z = vals[4] | ((u32)vals[5] << 16);  lo.w = vals[6] | ((u32)vals[7] << 16);
  hi.x = vals[8] | ((u32)vals[9] << 16);  hi.y = vals[10] | ((u32)vals[11] << 16);
  hi.z = vals[12] | ((u32)vals[13] << 16); hi.w = vals[14] | ((u32)vals[15] << 16);
  u16* dst = xmr + ((size_t)n * NPADT + 100 + tv) * 64 + q * 16;
  *(uint4*)dst = lo;
  *(uint4*)(dst + 8) = hi;
  __shared__ float red[4][64];
  red[q][tvl] = msacc;
  __syncthreads();
  if (q == 0) msum[n * TV + tv] = red[0][tvl] + red[1][tvl] + red[2][tvl] + red[3][tvl];
}

// ---- wb[kc][k=dt*64+cin], bf16, PLAIN layout (A read direct from L2) --------
__global__ void k_w(const float* __restrict__ weight, u16* __restrict__ wb) {
  int i = blockIdx.x * 256 + threadIdx.x;      // 110592
  if (i >= 110592) return;
  int kc = i / KDIM, k = i % KDIM;
  int cin = k & 63, dt = k >> 6;
  wb[i] = f2bf(weight[(kc * 64 + cin) * 9 + dt]);
}

// ---- per (n,t): upd -> s, mask_ratio, m_bool, Bc ----------------------------
__global__ void k_prep(const float* __restrict__ msum, const float* __restrict__ A_g,
                       float* __restrict__ s_ws, float* __restrict__ mr_ws,
                       float* __restrict__ mb_ws, float* __restrict__ Bc_ws) {
  int b = blockIdx.x;                          // 8192 = n*256 + t
  int n = b >> 8, t = b & 255;
  int tid = threadIdx.x;                       // 64
  __shared__ float uc[25];
  if (tid < 25) {
    float upd = 0.f;
    for (int dt = 0; dt < 9; ++dt) {
      int tt = t + dt - 4;
      if (tt >= 0 && tt < 256) upd += msum[n * TV + tt * 25 + tid];
    }
    float u_c = fminf(fmaxf(upd, 0.f), 1.f);
    float ratio = 576.f / (upd + 1e-8f);
    s_ws[n * TV + t * 25 + tid] = ratio * u_c * u_c;  // coeff of raw in out
    uc[tid] = u_c;
  }
  __syncthreads();
  if (tid < 25) {
    int w = tid;
    float M = 0.f;
    for (int k = 0; k < 3; ++k) {
      float acc = 0.f;
      for (int v = 0; v < 25; ++v) acc += uc[v] * A_g[(k * 25 + v) * 25 + w];
      Bc_ws[((size_t)(n * 3 + k) * 256 + t) * 25 + w] = acc;
      M += acc;
    }
    float mbv = (M != 0.f) ? 1.f : 0.f;
    mr_ws[n * TV + t * 25 + w] = mbv / (M + 1e-8f);
    mb_ws[n * TV + t * 25 + w] = mbv;
  }
}

// ---- m_bool: broadcast mb row over all 64 c, coalesced ----------------------
__global__ void k_mb(const float* __restrict__ mb_ws, float* __restrict__ out) {
  const int c = blockIdx.x, n = blockIdx.y;    // grid (64, 32), block 256
  const size_t base = (size_t)MB_OFF + (size_t)(n * 64 + c) * 6400;
  const float* src = mb_ws + n * TV;
  for (int j = threadIdx.x; j < 6400; j += 256)
    out[base + j] = src[j];
}

// ---- FUSED: implicit-GEMM + MFMA (k,v)-contraction + coalesced epilogue -----
// Block (tg, n): 1024 threads, 16 waves = 4(M) x 4(N). Wave cols: wn<3 -> 4
// frags (64 cols), wn=3 -> 1 frag (cols 192-207; 200-207 dead, guarded).
// K-loop: NO barriers — A from global (L2) w/ 1-step reg prefetch, B from xwin.
__global__ __launch_bounds__(1024, 4) void k_fused(
    const u16* __restrict__ xmr, const u16* __restrict__ wb,
    const float* __restrict__ s_g, const float* __restrict__ A_g,
    const float* __restrict__ Bc_g, const float* __restrict__ mr_g,
    const float* __restrict__ bias_g, float* __restrict__ out) {
  __shared__ __align__(16) char ring[63136];

  const int tid = threadIdx.x;
  const int tg = blockIdx.x;                  // 0..31 (8-t group)
  const int n = blockIdx.y;                   // 0..31
  const int tv0 = tg * 200;
  const int lane = tid & 63, wid = tid >> 6;
  const int wm = wid >> 2, wn = wid & 3;
  const int lrow = lane & 15, lgrp = lane >> 4;
  const int nf = (wn == 3) ? 1 : 4, colb = wn * 64;

  const u16* xmn = xmr + (size_t)n * NPADT * 64;
  u16* xwin = (u16*)(ring);

  f32x4 acc[3][4] = {};

  // ---- prologue: stage whole B window (51 loads), single barrier ------------
  {
    // window rows [tv0, tv0+408) padded; tv0 % 8 == 0 -> swizzle key invariant
    const int srow_g = lane >> 3, sl = (lane & 7) ^ (lane >> 3);  // per-lane
    for (int t = wid; t < 51; t += 16) {
      const u16* src = xmn + ((size_t)(tv0 + t * 8 + srow_g) * 64 + sl * 8);
      gload_lds16(src, xwin + t * 512);
    }
  }
  // A row base for this thread's 3 M-frags (plain wb layout)
  const u16* ap[3];
#pragma unroll
  for (int m = 0; m < 3; ++m)
    ap[m] = wb + (size_t)(wm * 48 + m * 16 + lrow) * KDIM + lgrp * 8;

  short8 afc[3], afn[3];
#pragma unroll
  for (int m = 0; m < 3; ++m) afc[m] = *(const short8*)(ap[m]);  // ks=0

  VMCNT(0);
  __builtin_amdgcn_s_barrier();      // xwin visible to all waves
  asm volatile("" ::: "memory");

  // ---- K-loop: 18 steps, barrier-free --------------------------------------
  for (int ks = 0; ks < 18; ++ks) {
    if (ks < 17) {                             // prefetch A(ks+1) into regs
#pragma unroll
      for (int m = 0; m < 3; ++m)
        afn[m] = *(const short8*)(ap[m] + (ks + 1) * 32);
    }
    const int dt = ks >> 1;
    const int rbase = 100 + (dt - 4) * 25 + colb + lrow;   // xwin row for ct=0
    const int slb = (ks & 1) * 4 + lgrp;                   // logical 16B slot
#pragma unroll
    for (int ct = 0; ct < 4; ++ct) {
      if (ct < nf) {
        int srow = rbase + ct * 16;
        short8 bfr = *(const short8*)&xwin[srow * 64 + ((slb ^ (srow & 7)) << 3)];
#pragma unroll
        for (int m = 0; m < 3; ++m)
          acc[m][ct] = __builtin_amdgcn_mfma_f32_16x16x32_bf16(afc[m], bfr, acc[m][ct], 0, 0, 0);
      }
    }
#pragma unroll
    for (int m = 0; m < 3; ++m) afc[m] = afn[m];
  }

  // ---- epilogue setup: zero Pl, stage Ab/Bcs/mrs/bias/ss -------------------
  __syncthreads();                     // all xwin reads done; safe to alias
  u16*   Plu   = (u16*)ring;           // [64][336]: tcol = t*40+v, pads zero
  u16*   Abu   = (u16*)(ring + L_AB);  // [3k][2nt][16w][32v] bf16 B-frag layout
  float* Bcsf  = (float*)(ring + L_BCS);
  float* mrsf  = (float*)(ring + L_MRS);
  float* biasf = (float*)(ring + L_BIAS);
  float* ssf   = (float*)(ring + L_SS);
  for (int i = tid; i < 10752; i += 1024) ((u32*)ring)[i] = 0;  // zero Pl (43KB)
  for (int i = tid; i < 3072; i += 1024) {
    int kk = i >> 10, r = i & 1023;
    int nt = r >> 9, rr = r & 511, wl = rr >> 5, v = rr & 31;
    int w = nt * 16 + wl;
    float val = (v < 25 && w < 25) ? A_g[(kk * 25 + v) * 25 + w] : 0.f;
    Abu[i] = f2bf(val);
  }
  if (tid < 600) {
    int k = tid / 200, t = (tid % 200) / 25, w = tid % 25;
    Bcsf[tid] = Bc_g[((size_t)(n * 3 + k) * 256 + tg * 8 + t) * 25 + w];
  }
  if (tid < 200) {
    mrsf[tid] = mr_g[n * TV + tv0 + tid];
    ssf[tid]  = s_g[n * TV + tv0 + tid];
  }
  if (tid >= 512 && tid < 704) biasf[tid - 512] = bias_g[tid - 512];
  __syncthreads();

  // ---- MFMA contraction: y(ct,w) = sum_v P(ct,v) * A(v,w), per-k -----------
  f32x4 yacc[2][2] = {};
  for (int k = 0; k < 3; ++k) {
    // stage Pl_k = bf16(acc * s) for rows of this k
#pragma unroll
    for (int m = 0; m < 3; ++m) {
      int R = wm * 48 + m * 16 + lgrp * 4;
      if ((R >> 6) == k) {
        int cb = R & 63;
#pragma unroll
        for (int ct = 0; ct < 4; ++ct) {
          if (ct < nf) {
            int col = colb + ct * 16 + lrow;
            if (col < 200) {
              int t = col / 25, v = col - t * 25;
              float sv = ssf[col];
              int tc = t * 40 + v;
#pragma unroll
              for (int r = 0; r < 4; ++r)
                Plu[(cb + r) * 336 + tc] = f2bf(acc[m][ct][r] * sv);
            }
          }
        }
      }
    }
    __syncthreads();
    // contraction MFMAs: wave owns M-tiles {wid*2, wid*2+1}
    short8 pb[2];
#pragma unroll
    for (int nt = 0; nt < 2; ++nt)
      pb[nt] = *(const short8*)&Abu[((k * 2 + nt) * 16 + lrow) * 32 + lgrp * 8];
#pragma unroll
    for (int mi = 0; mi < 2; ++mi) {
      int mt = wid * 2 + mi;
      const short8 pa = *(const short8*)
          &Plu[(mt * 2 + (lrow >> 3)) * 336 + (lrow & 7) * 40 + lgrp * 8];
#pragma unroll
      for (int nt = 0; nt < 2; ++nt)
        yacc[mi][nt] = __builtin_amdgcn_mfma_f32_16x16x32_bf16(pa, pb[nt], yacc[mi][nt], 0, 0, 0);
    }
    __syncthreads();                   // before next k overwrites Pl
  }

  // ---- finalize + transposed coalesced y writes ----------------------------
  // yacc[mi][nt][r]: row ct = (wid*2+mi)*16 + lgrp*4 + r, col w = nt*16 + lrow
  float (*Ysf)[201] = (float(*)[201])ring;     // aliases Pl, barrier-separated
  const size_t base_n = (size_t)(n * 64) * 6400 + tv0;
#pragma unroll
  for (int half = 0; half < 2; ++half) {
    __syncthreads();
    if ((wid >> 3) == half) {
#pragma unroll
      for (int mi = 0; mi < 2; ++mi)
#pragma unroll
        for (int nt = 0; nt < 2; ++nt) {
          int w = nt * 16 + lrow;
          if (w < 25) {
#pragma unroll
            for (int r = 0; r < 4; ++r) {
              int ct = (wid * 2 + mi) * 16 + lgrp * 4 + r;
              int c = ct >> 3, t = ct & 7;
              float bt = biasf[c] * Bcsf[t * 25 + w] +
                         biasf[64 + c] * Bcsf[200 + t * 25 + w] +
                         biasf[128 + c] * Bcsf[400 + t * 25 + w];
              Ysf[c & 31][t * 25 + w] = (yacc[mi][nt][r] + bt) * mrsf[t * 25 + w];
            }
          }
        }
    }
    __syncthreads();
    for (int i = tid; i < 6400; i += 1024) {
      int ch = i / 200, j = i % 200;
      out[base_n + (size_t)(half * 32 + ch) * 6400 + j] = Ysf[ch][j];
    }
  }
}

extern "C" void kernel_launch(void* const* d_in, const int* in_sizes, int n_in,
                              void* d_out, int out_size, void* d_ws, size_t ws_size,
                              hipStream_t stream) {
  const float* x      = (const float*)d_in[0];
  const float* A      = (const float*)d_in[1];
  const float* mask   = (const float*)d_in[2];
  const float* weight = (const float*)d_in[3];
  const float* bias   = (const float*)d_in[4];
  float* out = (float*)d_out;
  char* ws = (char*)d_ws;

  u16*   xmr   = (u16*)(ws);
  u16*   wb    = (u16*)(ws + OFF_WB);
  float* msum  = (float*)(ws + OFF_MSUM);
  float* s_ws  = (float*)(ws + OFF_S);
  float* mr_ws = (float*)(ws + OFF_MR);
  float* mb_ws = (float*)(ws + OFF_MB);
  float* Bc_ws = (float*)(ws + OFF_BC);

  k_pad<<<256, 256, 0, stream>>>(xmr);
  k_xmT<<<dim3(100, 32), 256, 0, stream>>>(x, mask, xmr, msum);
  k_w<<<432, 256, 0, stream>>>(weight, wb);
  k_prep<<<8192, 64, 0, stream>>>(msum, A, s_ws, mr_ws, mb_ws, Bc_ws);

  hipMemcpyAsync(out + Y_SIZE, A, 1875 * sizeof(float),
                 hipMemcpyDeviceToDevice, stream);

  k_mb<<<dim3(64, 32), 256, 0, stream>>>(mb_ws, out);
  k_fused<<<dim3(32, 32), 1024, 0, stream>>>(xmr, wb, s_ws, A, Bc_ws, mr_ws,
                                             bias, out);
}